// Round 1
// baseline (679.872 us; speedup 1.0000x reference)
//
#include <hip/hip_runtime.h>
#include <hip/hip_bf16.h>

#define CCH   128      // channels
#define D_TOT 2304     // flat feature dim
#define NT    16       // nodes per workgroup

typedef float f32x4 __attribute__((ext_vector_type(4)));
typedef short s16x8 __attribute__((ext_vector_type(8)));

__device__ __forceinline__ unsigned short f32_to_bf16(float f) {
    union { float f; unsigned u; } v; v.f = f;
    unsigned r = v.u + 0x7fffu + ((v.u >> 16) & 1u);   // RNE
    return (unsigned short)(r >> 16);
}

// One workgroup: 16 nodes x one irrep block (ML = 2l+1 in {1,3,5}).
// GEMM: rows = 16*ML (n,m pairs), cols = 128 (output channel d), K = 128 (c).
// out[n, off + d*ML + m] = sum_c x[n, off + c*ML + m] * (W + I)[d][c]
template<int ML>
__global__ __launch_bounds__(256)
void irrep_mix_kernel(const float* __restrict__ x,
                      const float* __restrict__ Wa,
                      const float* __restrict__ Wb,
                      float* __restrict__ out,
                      int off_a, int off_b, int nblocks_x)
{
    constexpr int ROWS = NT * ML;        // 16 / 48 / 80
    constexpr int RT   = ROWS / 16;      // 1 / 3 / 5 row-tiles
    constexpr int BLK  = CCH * ML;       // floats per node-block
    constexpr int LDSS = 136;            // padded LDS row stride (bf16 elems, 272B)

    __shared__ __attribute__((aligned(16))) unsigned short lds[ROWS * LDSS];

    const int sel = blockIdx.y;
    const int off = sel ? off_b : off_a;
    const float* __restrict__ W = sel ? Wb : Wa;
    const size_t nbase = (size_t)blockIdx.x * NT;

    const int tid = threadIdx.x;
    const int wv  = tid >> 6;       // wave 0..3 -> col range [wv*32, wv*32+32)
    const int ln  = tid & 63;
    const int l16 = ln & 15;
    const int lhi = ln >> 4;        // 0..3

    // ---------- B fragments: (W^T + I), registers, once per wave ----------
    s16x8 bfrag[2][4];
    #pragma unroll
    for (int t = 0; t < 2; ++t) {
        const int d = wv * 32 + t * 16 + l16;          // output channel (col)
        #pragma unroll
        for (int s = 0; s < 4; ++s) {
            const int k0 = s * 32 + lhi * 8;           // k = input channel c
            const float4 w0 = *reinterpret_cast<const float4*>(W + d * CCH + k0);
            const float4 w1 = *reinterpret_cast<const float4*>(W + d * CCH + k0 + 4);
            const float wv8[8] = {w0.x, w0.y, w0.z, w0.w, w1.x, w1.y, w1.z, w1.w};
            s16x8 b;
            #pragma unroll
            for (int j = 0; j < 8; ++j) {
                const float val = wv8[j] + ((d == k0 + j) ? 1.0f : 0.0f);
                b[j] = (short)f32_to_bf16(val);
            }
            bfrag[t][s] = b;
        }
    }

    // ---------- stage x tile -> LDS bf16, de-interleaved to [row][c] ----------
    // flat f in [0, NT*BLK): node nl = f/BLK, r = f%BLK, c = r/ML, m = r%ML
    {
        const float* src = x + nbase * D_TOT + off;
        constexpr int ITER = (NT * BLK) / (256 * 4);   // 2 / 6 / 10
        #pragma unroll
        for (int i = 0; i < ITER; ++i) {
            const int f  = (i * 256 + tid) * 4;        // stays inside one node-block
            const int nl = f / BLK;
            const int r  = f - nl * BLK;
            const float4 v = *reinterpret_cast<const float4*>(src + (size_t)nl * D_TOT + r);
            const float ve[4] = {v.x, v.y, v.z, v.w};
            #pragma unroll
            for (int j = 0; j < 4; ++j) {
                const int rr = r + j;
                const int cc = rr / ML;
                const int mm = rr - cc * ML;
                lds[(nl * ML + mm) * LDSS + cc] = f32_to_bf16(ve[j]);
            }
        }
    }
    __syncthreads();

    // ---------- MFMA: acc[rt][t] over K=128 ----------
    f32x4 acc[RT][2];
    #pragma unroll
    for (int rt = 0; rt < RT; ++rt)
        #pragma unroll
        for (int t = 0; t < 2; ++t)
            acc[rt][t] = (f32x4){0.f, 0.f, 0.f, 0.f};

    #pragma unroll
    for (int rt = 0; rt < RT; ++rt) {
        const int row = rt * 16 + l16;
        #pragma unroll
        for (int s = 0; s < 4; ++s) {
            const int k0 = s * 32 + lhi * 8;
            const s16x8 a = *reinterpret_cast<const s16x8*>(&lds[row * LDSS + k0]);
            acc[rt][0] = __builtin_amdgcn_mfma_f32_16x16x32_bf16(a, bfrag[0][s], acc[rt][0], 0, 0, 0);
            acc[rt][1] = __builtin_amdgcn_mfma_f32_16x16x32_bf16(a, bfrag[1][s], acc[rt][1], 0, 0, 0);
        }
    }

    // ---------- epilogue: D[row][col], col=lane&15, row=(lane>>4)*4+j ----------
    const size_t out_base = nbase * D_TOT + off;
    #pragma unroll
    for (int rt = 0; rt < RT; ++rt) {
        #pragma unroll
        for (int t = 0; t < 2; ++t) {
            const int col = wv * 32 + t * 16 + l16;
            #pragma unroll
            for (int j = 0; j < 4; ++j) {
                const int row = rt * 16 + lhi * 4 + j;
                const int nl  = row / ML;
                const int mm  = row - nl * ML;
                out[out_base + (size_t)nl * D_TOT + col * ML + mm] = acc[rt][t][j];
            }
        }
    }
}

extern "C" void kernel_launch(void* const* d_in, const int* in_sizes, int n_in,
                              void* d_out, int out_size, void* d_ws, size_t ws_size,
                              hipStream_t stream) {
    const float* x   = (const float*)d_in[0];
    const float* W0p = (const float*)d_in[1];
    const float* W0m = (const float*)d_in[2];
    const float* W1p = (const float*)d_in[3];
    const float* W1m = (const float*)d_in[4];
    const float* W2p = (const float*)d_in[5];
    const float* W2m = (const float*)d_in[6];
    float* out = (float*)d_out;

    const int N   = in_sizes[0] / D_TOT;   // 100000
    const int nbx = N / NT;                // 6250 (exact)

    dim3 blk(256);
    dim3 grid(nbx, 2);
    // block offsets (floats): l=0e:0, 0o:128, 1e:256, 1o:640, 2e:1024, 2o:1664
    irrep_mix_kernel<1><<<grid, blk, 0, stream>>>(x, W0p, W0m, out, 0,    128,  nbx);
    irrep_mix_kernel<3><<<grid, blk, 0, stream>>>(x, W1p, W1m, out, 256,  640,  nbx);
    irrep_mix_kernel<5><<<grid, blk, 0, stream>>>(x, W2p, W2m, out, 1024, 1664, nbx);
}

// Round 2
// 531.267 us; speedup vs baseline: 1.2797x; 1.2797x over previous
//
#include <hip/hip_runtime.h>
#include <hip/hip_bf16.h>

#define CCH   128      // channels
#define D_TOT 2304     // flat feature dim
#define NT    16       // nodes per workgroup

typedef float f32x4 __attribute__((ext_vector_type(4)));
typedef short s16x8 __attribute__((ext_vector_type(8)));

__device__ __forceinline__ unsigned short f32_to_bf16(float f) {
    union { float f; unsigned u; } v; v.f = f;
    unsigned r = v.u + 0x7fffu + ((v.u >> 16) & 1u);   // RNE
    return (unsigned short)(r >> 16);
}

// One workgroup: 16 nodes x one irrep block (ML = 2l+1 in {1,3,5}).
// GEMM: rows = 16*ML (n,m pairs), cols = 128 (output channel d), K = 128 (c).
// out[n, off + d*ML + m] = sum_c x[n, off + c*ML + m] * (W + I)[d][c]
// Epilogue re-interleaves through LDS so global stores are contiguous float4.
template<int ML>
__global__ __launch_bounds__(256)
void irrep_mix_kernel(const float* __restrict__ x,
                      const float* __restrict__ Wa,
                      const float* __restrict__ Wb,
                      float* __restrict__ out,
                      int off_a, int off_b)
{
    constexpr int ROWS = NT * ML;        // 16 / 48 / 80
    constexpr int RT   = ROWS / 16;      // 1 / 3 / 5 row-tiles
    constexpr int BLK  = CCH * ML;       // floats per node-block
    constexpr int LDSS = 136;            // padded LDS row stride (bf16 elems, 272B)
    constexpr int ITER = (NT * BLK) / (256 * 4);   // 2 / 6 / 10

    constexpr size_t IN_BYTES  = (size_t)ROWS * LDSS * 2;
    constexpr size_t OUT_BYTES = (size_t)NT * BLK * 4;
    constexpr size_t SMEM_BYTES = OUT_BYTES > IN_BYTES ? OUT_BYTES : IN_BYTES;
    __shared__ __attribute__((aligned(16))) char smem[SMEM_BYTES];
    unsigned short* __restrict__ lin  = (unsigned short*)smem;  // staged bf16 A
    float*          __restrict__ lout = (float*)smem;           // re-interleaved out

    const int sel = blockIdx.y;
    const int off = sel ? off_b : off_a;
    const float* __restrict__ W = sel ? Wb : Wa;
    const size_t nbase = (size_t)blockIdx.x * NT;

    const int tid = threadIdx.x;
    const int wv  = tid >> 6;       // wave 0..3 -> col range [wv*32, wv*32+32)
    const int ln  = tid & 63;
    const int l16 = ln & 15;
    const int lhi = ln >> 4;        // 0..3

    // ---------- B fragments: (W^T + I), registers, once per wave ----------
    s16x8 bfrag[2][4];
    #pragma unroll
    for (int t = 0; t < 2; ++t) {
        const int d = wv * 32 + t * 16 + l16;          // output channel (col)
        #pragma unroll
        for (int s = 0; s < 4; ++s) {
            const int k0 = s * 32 + lhi * 8;           // k = input channel c
            const float4 w0 = *reinterpret_cast<const float4*>(W + d * CCH + k0);
            const float4 w1 = *reinterpret_cast<const float4*>(W + d * CCH + k0 + 4);
            const float wv8[8] = {w0.x, w0.y, w0.z, w0.w, w1.x, w1.y, w1.z, w1.w};
            s16x8 b;
            #pragma unroll
            for (int j = 0; j < 8; ++j) {
                const float val = wv8[j] + ((d == k0 + j) ? 1.0f : 0.0f);
                b[j] = (short)f32_to_bf16(val);
            }
            bfrag[t][s] = b;
        }
    }

    // ---------- stage x tile -> LDS bf16, de-interleaved to [row][c] ----------
    // flat f in [0, NT*BLK): node nl = f/BLK, r = f%BLK, c = r/ML, m = r%ML
    {
        const float* src = x + nbase * D_TOT + off;
        #pragma unroll
        for (int i = 0; i < ITER; ++i) {
            const int f  = (i * 256 + tid) * 4;        // stays inside one node-block
            const int nl = f / BLK;
            const int r  = f - nl * BLK;
            const float4 v = *reinterpret_cast<const float4*>(src + (size_t)nl * D_TOT + r);
            const float ve[4] = {v.x, v.y, v.z, v.w};
            #pragma unroll
            for (int j = 0; j < 4; ++j) {
                const int rr = r + j;
                const int cc = rr / ML;
                const int mm = rr - cc * ML;
                lin[(nl * ML + mm) * LDSS + cc] = f32_to_bf16(ve[j]);
            }
        }
    }
    __syncthreads();

    // ---------- MFMA: acc[rt][t] over K=128 ----------
    f32x4 acc[RT][2];
    #pragma unroll
    for (int rt = 0; rt < RT; ++rt)
        #pragma unroll
        for (int t = 0; t < 2; ++t)
            acc[rt][t] = (f32x4){0.f, 0.f, 0.f, 0.f};

    #pragma unroll
    for (int rt = 0; rt < RT; ++rt) {
        const int row = rt * 16 + l16;
        #pragma unroll
        for (int s = 0; s < 4; ++s) {
            const int k0 = s * 32 + lhi * 8;
            const s16x8 a = *reinterpret_cast<const s16x8*>(&lin[row * LDSS + k0]);
            acc[rt][0] = __builtin_amdgcn_mfma_f32_16x16x32_bf16(a, bfrag[0][s], acc[rt][0], 0, 0, 0);
            acc[rt][1] = __builtin_amdgcn_mfma_f32_16x16x32_bf16(a, bfrag[1][s], acc[rt][1], 0, 0, 0);
        }
    }
    __syncthreads();   // all MFMA reads of lin done before lout overwrites smem

    // ---------- epilogue A: scatter acc -> lout in OUTPUT (interleaved) layout ----
    // D layout: col=lane&15 (here col = wv*32+t*16+l16), row=(lane>>4)*4+j
    #pragma unroll
    for (int rt = 0; rt < RT; ++rt) {
        #pragma unroll
        for (int t = 0; t < 2; ++t) {
            const int col = wv * 32 + t * 16 + l16;
            #pragma unroll
            for (int j = 0; j < 4; ++j) {
                const int row = rt * 16 + lhi * 4 + j;
                const int nl  = row / ML;
                const int mm  = row - nl * ML;
                lout[nl * BLK + col * ML + mm] = acc[rt][t][j];
            }
        }
    }
    __syncthreads();

    // ---------- epilogue B: contiguous float4 stores (full-line density) ------
    {
        float* dst = out + nbase * D_TOT + off;
        #pragma unroll
        for (int i = 0; i < ITER; ++i) {
            const int f  = (i * 256 + tid) * 4;
            const int nl = f / BLK;
            const int r  = f - nl * BLK;
            const float4 v = *reinterpret_cast<const float4*>(&lout[f]);
            *reinterpret_cast<float4*>(dst + (size_t)nl * D_TOT + r) = v;
        }
    }
}

extern "C" void kernel_launch(void* const* d_in, const int* in_sizes, int n_in,
                              void* d_out, int out_size, void* d_ws, size_t ws_size,
                              hipStream_t stream) {
    const float* x   = (const float*)d_in[0];
    const float* W0p = (const float*)d_in[1];
    const float* W0m = (const float*)d_in[2];
    const float* W1p = (const float*)d_in[3];
    const float* W1m = (const float*)d_in[4];
    const float* W2p = (const float*)d_in[5];
    const float* W2m = (const float*)d_in[6];
    float* out = (float*)d_out;

    const int N   = in_sizes[0] / D_TOT;   // 100000
    const int nbx = N / NT;                // 6250 (exact)

    dim3 blk(256);
    dim3 grid(nbx, 2);
    // block offsets (floats): l=0e:0, 0o:128, 1e:256, 1o:640, 2e:1024, 2o:1664
    irrep_mix_kernel<1><<<grid, blk, 0, stream>>>(x, W0p, W0m, out, 0,    128);
    irrep_mix_kernel<3><<<grid, blk, 0, stream>>>(x, W1p, W1m, out, 256,  640);
    irrep_mix_kernel<5><<<grid, blk, 0, stream>>>(x, W2p, W2m, out, 1024, 1664);
}

// Round 3
// 464.205 us; speedup vs baseline: 1.4646x; 1.1445x over previous
//
#include <hip/hip_runtime.h>

typedef float f32x4 __attribute__((ext_vector_type(4)));
typedef short s16x8 __attribute__((ext_vector_type(8)));

__device__ __forceinline__ unsigned short f32_to_bf16(float f){
    union { float f; unsigned u; } v; v.f = f;
    unsigned r = v.u + 0x7fffu + ((v.u >> 16) & 1u);   // RNE
    return (unsigned short)(r >> 16);
}
__device__ __forceinline__ unsigned pack2(float a, float b){
    return (unsigned)f32_to_bf16(a) | ((unsigned)f32_to_bf16(b) << 16);
}

// ---------- W pre-convert: wbf[w][d][c] = bf16(W[d][c] + (d==c)) -------------
__global__ __launch_bounds__(256)
void wconv_kernel(const float* __restrict__ W0p, const float* __restrict__ W0m,
                  const float* __restrict__ W1p, const float* __restrict__ W1m,
                  const float* __restrict__ W2p, const float* __restrict__ W2m,
                  unsigned short* __restrict__ wbf)
{
    const int idx = blockIdx.x * 256 + threadIdx.x;   // 384 blocks * 256 = 98304
    const int w  = idx >> 14;
    const int rc = idx & 16383;
    const float* Wp;
    switch (w) {
        case 0: Wp = W0p; break;  case 1: Wp = W0m; break;
        case 2: Wp = W1p; break;  case 3: Wp = W1m; break;
        case 4: Wp = W2p; break;  default: Wp = W2m; break;
    }
    const float v = Wp[rc] + (((rc >> 7) == (rc & 127)) ? 1.0f : 0.0f);
    wbf[idx] = f32_to_bf16(v);
}

// ---------- l = 0 kernel: operand-swapped (A = W+I, B = x nodes) -------------
// D[d][node]: direct coalesced float4 stores, no output LDS staging.
__global__ __launch_bounds__(256)
void l0_kernel(const float* __restrict__ x, const unsigned short* __restrict__ wbf,
               float* __restrict__ out)
{
    constexpr int LDSS = 264;                     // bf16 elems per row (528 B, 16-al)
    __shared__ __attribute__((aligned(16))) unsigned short lin[16 * LDSS];

    const size_t nbase = (size_t)blockIdx.x * 16;
    const int tid = threadIdx.x;
    const int wv  = tid >> 6, ln = tid & 63;
    const int l16 = ln & 15,  lhi = ln >> 4;

    // stage: x[n][0..256) -> bf16 lin[n][c] (convert-only, contiguous)
    const float* src = x + nbase * 2304;
    #pragma unroll
    for (int i = 0; i < 4; ++i) {
        const int f  = i * 1024 + tid * 4;
        const int nl = f >> 8, c = f & 255;
        const float4 v = *reinterpret_cast<const float4*>(src + (size_t)nl * 2304 + c);
        uint2 p; p.x = pack2(v.x, v.y); p.y = pack2(v.z, v.w);
        *reinterpret_cast<uint2*>(&lin[nl * LDSS + c]) = p;
    }
    __syncthreads();

    const int b     = wv >> 1;            // block parity (0e / 0o)
    const int dbase = (wv & 1) * 64;
    const unsigned short* wb = wbf + b * 16384;

    f32x4 acc[4];
    #pragma unroll
    for (int dt = 0; dt < 4; ++dt) acc[dt] = (f32x4){0.f,0.f,0.f,0.f};

    #pragma unroll
    for (int s = 0; s < 4; ++s) {
        const int k0 = s * 32 + lhi * 8;
        const s16x8 bf = *reinterpret_cast<const s16x8*>(&lin[l16 * LDSS + b * 128 + k0]);
        #pragma unroll
        for (int dt = 0; dt < 4; ++dt) {
            const int d = dbase + dt * 16 + l16;
            const s16x8 af = *reinterpret_cast<const s16x8*>(wb + d * 128 + k0);
            acc[dt] = __builtin_amdgcn_mfma_f32_16x16x32_bf16(af, bf, acc[dt], 0, 0, 0);
        }
    }

    // store: lane l16 = node, regs j = consecutive d -> float4, fully coalesced
    float* dst = out + (nbase + l16) * 2304 + b * 128 + dbase + lhi * 4;
    #pragma unroll
    for (int dt = 0; dt < 4; ++dt) {
        float4 v; v.x = acc[dt][0]; v.y = acc[dt][1]; v.z = acc[dt][2]; v.w = acc[dt][3];
        *reinterpret_cast<float4*>(dst + dt * 16) = v;
    }
}

// ---------- l = 1,2 kernel: A = x rows (n,m), B = W+I cols; LDS out re-interleave
template<int ML, int NT>
__global__ __launch_bounds__(256)
void lx_kernel(const float* __restrict__ x, const unsigned short* __restrict__ wbf,
               float* __restrict__ out, int yoff0, int yoff1, int w0)
{
    constexpr int BLK  = 128 * ML;        // dwords per node-block
    constexpr int ROWS = NT * ML;         // 96 (3,32) / 80 (5,16)
    constexpr int RT   = ROWS / 16;       // 6 / 5
    constexpr int LDSS = 136;             // bf16 elems per lin row (272 B)
    constexpr int QPT  = (NT * 32) / 256; // channel-quads per thread: 4 / 2
    constexpr int ITER = NT * BLK / 1024; // flush float4 iters: 12 / 10
    constexpr int H    = (RT + 1) / 2;    // tiles per wave-half: 3 / 3

    constexpr size_t IN_B  = (size_t)ROWS * LDSS * 2;
    constexpr size_t OUT_B = (size_t)NT * BLK * 4;
    constexpr size_t SMEM  = OUT_B > IN_B ? OUT_B : IN_B;
    __shared__ __attribute__((aligned(16))) char smem[SMEM];
    unsigned short* lin  = (unsigned short*)smem;
    float*          lout = (float*)smem;

    const int yoff = blockIdx.y ? yoff1 : yoff0;
    const unsigned short* wb = wbf + (size_t)(w0 + blockIdx.y) * 16384;
    const size_t nbase = (size_t)blockIdx.x * NT;

    const int tid = threadIdx.x;
    const int wv  = tid >> 6, ln = tid & 63;
    const int l16 = ln & 15,  lhi = ln >> 4;

    // ---- stage: per thread, QPT quads of 4 channels x all m (aligned float4s)
    const float* src = x + nbase * 2304 + yoff;
    #pragma unroll
    for (int i = 0; i < QPT; ++i) {
        const int q  = i * 256 + tid;
        const int nl = q >> 5;
        const int c  = (q & 31) * 4;
        const float* p = src + (size_t)nl * 2304 + c * ML;
        float v[4 * ML];
        #pragma unroll
        for (int j = 0; j < ML; ++j) {
            const float4 t = *reinterpret_cast<const float4*>(p + j * 4);
            v[j*4+0] = t.x; v[j*4+1] = t.y; v[j*4+2] = t.z; v[j*4+3] = t.w;
        }
        #pragma unroll
        for (int mm = 0; mm < ML; ++mm) {
            uint2 pk;
            pk.x = pack2(v[mm], v[mm + ML]);
            pk.y = pack2(v[mm + 2*ML], v[mm + 3*ML]);
            const int row = nl * ML + mm;
            *reinterpret_cast<uint2*>(&lin[row * LDSS + c]) = pk;
        }
    }
    __syncthreads();

    // ---- MFMA: wave = (tile-half, col-half)
    const int th = wv >> 1, ch = wv & 1;
    const int t0 = th * H;

    f32x4 acc[H][4];
    #pragma unroll
    for (int rt = 0; rt < H; ++rt)
        #pragma unroll
        for (int tf = 0; tf < 4; ++tf) acc[rt][tf] = (f32x4){0.f,0.f,0.f,0.f};

    #pragma unroll
    for (int s = 0; s < 4; ++s) {
        const int k0 = s * 32 + lhi * 8;
        s16x8 bf[4];
        #pragma unroll
        for (int tf = 0; tf < 4; ++tf) {
            const int d = ch * 64 + tf * 16 + l16;
            bf[tf] = *reinterpret_cast<const s16x8*>(wb + d * 128 + k0);
        }
        #pragma unroll
        for (int rt = 0; rt < H; ++rt) {
            if (t0 + rt < RT) {
                const int row = (t0 + rt) * 16 + l16;
                const s16x8 af = *reinterpret_cast<const s16x8*>(&lin[row * LDSS + k0]);
                #pragma unroll
                for (int tf = 0; tf < 4; ++tf)
                    acc[rt][tf] = __builtin_amdgcn_mfma_f32_16x16x32_bf16(af, bf[tf], acc[rt][tf], 0, 0, 0);
            }
        }
    }
    __syncthreads();   // lin dead; lout takes over smem

    // ---- scatter acc -> lout in output (interleaved) layout
    #pragma unroll
    for (int rt = 0; rt < H; ++rt) {
        if (t0 + rt < RT) {
            #pragma unroll
            for (int tf = 0; tf < 4; ++tf) {
                const int col = ch * 64 + tf * 16 + l16;
                #pragma unroll
                for (int j = 0; j < 4; ++j) {
                    const int row = (t0 + rt) * 16 + lhi * 4 + j;
                    const int nl  = row / ML;
                    const int mm  = row - nl * ML;
                    lout[nl * BLK + col * ML + mm] = acc[rt][tf][j];
                }
            }
        }
    }
    __syncthreads();

    // ---- flush: contiguous float4 stores
    float* dst = out + nbase * 2304 + yoff;
    #pragma unroll
    for (int i = 0; i < ITER; ++i) {
        const int f  = (i * 256 + tid) * 4;
        const int nl = f / BLK;
        const int r  = f - nl * BLK;
        *reinterpret_cast<float4*>(dst + (size_t)nl * 2304 + r) =
            *reinterpret_cast<const float4*>(&lout[f]);
    }
}

extern "C" void kernel_launch(void* const* d_in, const int* in_sizes, int n_in,
                              void* d_out, int out_size, void* d_ws, size_t ws_size,
                              hipStream_t stream) {
    const float* x   = (const float*)d_in[0];
    const float* W0p = (const float*)d_in[1];
    const float* W0m = (const float*)d_in[2];
    const float* W1p = (const float*)d_in[3];
    const float* W1m = (const float*)d_in[4];
    const float* W2p = (const float*)d_in[5];
    const float* W2m = (const float*)d_in[6];
    float* out = (float*)d_out;
    unsigned short* wbf = (unsigned short*)d_ws;   // 6*128*128 bf16 = 196.6 KB

    const int N = in_sizes[0] / 2304;   // 100000

    wconv_kernel<<<384, 256, 0, stream>>>(W0p, W0m, W1p, W1m, W2p, W2m, wbf);

    // block offsets (floats): 0e:0, 0o:128 | 1e:256, 1o:640 | 2e:1024, 2o:1664
    lx_kernel<5,16><<<dim3(N/16, 2), 256, 0, stream>>>(x, wbf, out, 1024, 1664, 4);
    lx_kernel<3,32><<<dim3(N/32, 2), 256, 0, stream>>>(x, wbf, out, 256,  640,  2);
    l0_kernel      <<<N/16,          256, 0, stream>>>(x, wbf, out);
}